// Round 5
// baseline (419.773 us; speedup 1.0000x reference)
//
#include <hip/hip_runtime.h>
#include <math.h>

#define B_   16
#define V_   16
#define C_   64
#define M_   32
#define CM_  16
#define D_   128
#define OUT_ 600
#define NSEQ 256      // B*V
#define NROW 8192     // B*V*M

typedef __attribute__((ext_vector_type(8))) short bf16x8;
typedef __attribute__((ext_vector_type(4))) short bf16x4;
typedef __attribute__((ext_vector_type(4))) float f32x4;
typedef __attribute__((ext_vector_type(2))) unsigned int u32x2;

__device__ __forceinline__ unsigned short f2bf(float x) {
  union { float f; unsigned u; } v; v.f = x;
  unsigned r = v.u + 0x7fff + ((v.u >> 16) & 1);   // RNE
  return (unsigned short)(r >> 16);
}
__device__ __forceinline__ float bf2f(short s) {
  union { unsigned u; float f; } v;
  v.u = ((unsigned)(unsigned short)s) << 16;
  return v.f;
}
__device__ __forceinline__ float u2f(unsigned u) {
  union { unsigned u; float f; } v; v.u = u; return v.f;
}
// fast sigmoid / tanh: native v_exp + v_rcp (~5 inst), saturate correctly
__device__ __forceinline__ float fsig(float x)  { return __fdividef(1.f, 1.f + __expf(-x)); }
__device__ __forceinline__ float ftanh(float x) { return 1.f - 2.f*__fdividef(1.f, __expf(2.f*x) + 1.f); }

// LDS-only barrier: drains LDS ops for cross-wave visibility but does NOT
// drain vmcnt — in-flight global (gi prefetch) loads survive the barrier.
__device__ __forceinline__ void ldsbar() {
  asm volatile("s_waitcnt lgkmcnt(0)" ::: "memory");
  __builtin_amdgcn_s_barrier();
  asm volatile("" ::: "memory");
}

// manual 8B global load (2 dwords) — keeps waitcnt control OUT of the
// compiler's hands; paired with explicit counted s_waitcnt vmcnt(N).
#define GLD(dst, ptr, offstr) \
  asm volatile("global_load_dwordx2 %0, %1, off offset:" offstr \
               : "=v"(dst) : "v"(ptr) : "memory")

// ---- workspace layout (float units; bf16 arrays are short* views) ----
constexpr int OFF_VIS   = 0;                               // fp32 [3][256][128]
constexpr int OFF_VISB  = 98304;                           // bf16 [3][256][128]
constexpr int OFF_MONB  = 147456;                          // bf16 [2][8192][128]
constexpr int OFF_TOTB  = 1196032;                         // bf16 [2][8192][128]
constexpr int OFF_W12T  = 2244608;                         // bf16 [8][128n][256k]
constexpr int OFF_WIHB  = 2375680;                         // bf16 [5][384n][128k]
constexpr int OFF_WIHTV = 2498560;                         // fp32 [4][128][384]
constexpr int OFF_XE    = 2695168;                         // fp32 [2][256][128]
constexpr int OFF_GI    = 2760704;                         // bf16 gi3[8][64][32][384][4]
constexpr int OFF_LAST  = 27926528;                        // fp32 [8][256][128]
constexpr int OFF_VH    = 29171712;                        // fp32 [10][16][128] (unused now)

// =====================================================================
// prep+vis merged — verified; THIS ROUND: +38 tail blocks init out=bias
// (runs before k_vgh's atomicAdds by stream order).
// =====================================================================
__global__ __launch_bounds__(256) void k_prepvis(
    const float* __restrict__ Wself, const float* __restrict__ Wmsg,
    const float* __restrict__ mWih,  const float* __restrict__ vWih,
    const float* __restrict__ wgt,   const float* __restrict__ age,
    const float* __restrict__ fwW,   const float* __restrict__ fwB,
    const float* __restrict__ faW,   const float* __restrict__ faB,
    const int* __restrict__ cc, const int* __restrict__ cp, const int* __restrict__ cd,
    const float* __restrict__ ec, const float* __restrict__ ep, const float* __restrict__ ed,
    const float* __restrict__ bp,
    short* __restrict__ w12t, short* __restrict__ wihb,
    float* __restrict__ wihTv, float* __restrict__ xe,
    float* __restrict__ vis, short* __restrict__ visb,
    float* __restrict__ outb)
{
  int bx = blockIdx.x, tid = threadIdx.x;
  if (bx < 1024) {                      // w12t[pt][n][k] = bf16 combined
    int lin = bx*256 + tid;             // < 262144
    int pt = lin >> 15, rem = lin & 32767;
    int n = rem >> 8, k = rem & 255;
    float v;
    if (k < 128) v = Wself[pt*16384 + k*128 + n] - Wmsg[pt*16384 + k*128 + n]*(1.f/3.f);
    else         v = Wmsg[pt*16384 + (k-128)*128 + n]*(1.f/3.f);
    w12t[lin] = (short)f2bf(v);
  } else if (bx < 1984) {               // wihb = bf16(mWih) elementwise
    int lin = (bx-1024)*256 + tid;      // < 245760
    wihb[lin] = (short)f2bf(mWih[lin]);
  } else if (bx < 2752) {               // vgru Wih transpose fp32
    int lin = (bx-1984)*256 + tid;      // < 196608
    int g = lin / 49152, rem2 = lin % 49152;
    int k = rem2 / 384, j = rem2 % 384;
    wihTv[lin] = vWih[g*49152 + j*128 + k];
  } else if (bx < 3008) {               // xe for weight / age
    int lin = (bx-2752)*256 + tid;      // < 65536
    int which = lin >> 15, rem2 = lin & 32767;
    int n = rem2 >> 7, d = rem2 & 127;
    float x  = which ? age[n] : wgt[n];
    float Wv = which ? faW[d] : fwW[d];
    float bb = which ? faB[d] : fwB[d];
    xe[lin] = (x != 0.0f) ? (x*Wv + bb) : 0.0f;
  } else if (bx < 3392) {               // visit-event sum pools
    int idx = (bx-3008)*256 + tid;      // < 98304
    int type = idx >> 15;
    int r = idx & 32767;
    int bv = r >> 7, d = r & 127;
    const int*   codes = (type==0) ? cc : (type==1) ? cp : cd;
    const float* emb   = (type==0) ? ec : (type==1) ? ep : ed;
    float acc = 0.f;
    for (int c = 0; c < C_; ++c) {
      int code = codes[bv*C_ + c];
      acc += emb[code*D_ + d];
    }
    vis [(type*NSEQ + bv)*D_ + d] = acc;
    visb[(type*NSEQ + bv)*D_ + d] = (short)f2bf(acc);
  } else {                              // out = bias init (for k_vgh atomics)
    int idx = (bx-3392)*256 + tid;      // < 9728
    if (idx < B_*OUT_) outb[idx] = bp[idx % OUT_];
  }
}

// =====================================================================
// monitor-event pools — unchanged (verified).
// =====================================================================
__global__ __launch_bounds__(128) void k_mon(
    const int* __restrict__ cli, const int* __restrict__ clv,
    const int* __restrict__ cii, const int* __restrict__ civ,
    const float* __restrict__ eli, const float* __restrict__ elv,
    const float* __restrict__ eii, const float* __restrict__ eiv,
    const float* __restrict__ vis,
    short* __restrict__ monb, short* __restrict__ totb)
{
  int p   = blockIdx.x >> 13;
  int bvm = blockIdx.x & 8191;
  int d   = threadIdx.x;
  const int* ci = p ? cii : cli;  const int* cv = p ? civ : clv;
  const float* ei = p ? eii : eli; const float* ev = p ? eiv : elv;
  float acc = 0.f;
  #pragma unroll
  for (int c = 0; c < CM_; ++c) {
    int iv = ci[bvm*CM_ + c];
    int vv = cv[bvm*CM_ + c];
    acc += ei[iv*D_ + d] * ev[vv*D_ + d];
  }
  int bv = bvm >> 5;
  float vsum = vis[bv*D_ + d] + vis[(NSEQ + bv)*D_ + d] + vis[(2*NSEQ + bv)*D_ + d];
  monb[(p*NROW + bvm)*D_ + d] = (short)f2bf(acc);
  totb[(p*NROW + bvm)*D_ + d] = (short)f2bf(acc + vsum);
}

// =====================================================================
// FUSED GNN+GI (MFMA bf16) — verified, unchanged.
// =====================================================================
__global__ __launch_bounds__(256, 4) void k_gg(
    const short* __restrict__ monb, const short* __restrict__ totb,
    const short* __restrict__ visb, const short* __restrict__ w12t,
    const short* __restrict__ wihb, const float* __restrict__ mbih,
    short* __restrict__ gi)
{
  const int pt = blockIdx.x >> 6;          // run 0..7
  const int rb = blockIdx.x & 63;
  const int p = pt >> 2, t = pt & 3;
  const int g = (pt % 4 == 0) ? (pt / 4) : (pt % 4 + 1);
  const int row0 = rb * 128;
  const int tid = threadIdx.x;
  const int w = tid >> 6, lane = tid & 63;
  const int c = lane & 15, q = lane >> 4;

  __shared__ short smem[2*128*72];         // 36864 B; Ys / giS alias
  short (*Xs)[72]  = (short(*)[72])smem;
  short (*Ws)[72]  = (short(*)[72])(smem + 128*72);
  short (*Ys)[136] = (short(*)[136])smem;
  float (*giS)[68] = (float(*)[68])smem;   // 128 x 68 fp32 = 34816 B

  const int rowL = tid >> 1, kc = tid & 1;
  const int rowG = row0 + rowL;
  const int bv = rowG >> 5;
  const int mg = w >> 1, ng = w & 1;

  f32x4 acc1[4][4];
  #pragma unroll
  for (int mi = 0; mi < 4; ++mi)
    #pragma unroll
    for (int ni = 0; ni < 4; ++ni) acc1[mi][ni] = (f32x4){0.f,0.f,0.f,0.f};

  const short* featp = (t == 0) ? (monb + ((size_t)p*NROW + rowG)*128)
                                : (visb + ((size_t)(t-1)*NSEQ + bv)*128);
  const short* totp  = totb + ((size_t)p*NROW + rowG)*128;
  const short* wrow  = w12t + ((size_t)pt*128 + rowL)*256;

  #pragma unroll 1
  for (int ks = 0; ks < 4; ++ks) {
    __syncthreads();
    int kg = ks*64 + kc*32;
    const short* srcX = (kg < 128) ? (featp + kg) : (totp + (kg - 128));
    const short* srcW = wrow + kg;
    short* dX = &Xs[rowL][kc*32];
    short* dW = &Ws[rowL][kc*32];
    #pragma unroll
    for (int i = 0; i < 4; ++i) {
      *(bf16x8*)(dX + 8*i) = *(const bf16x8*)(srcX + 8*i);
      *(bf16x8*)(dW + 8*i) = *(const bf16x8*)(srcW + 8*i);
    }
    __syncthreads();
    #pragma unroll
    for (int kk = 0; kk < 2; ++kk) {
      bf16x8 af[4], bfr[4];
      #pragma unroll
      for (int mi = 0; mi < 4; ++mi)
        af[mi] = *(const bf16x8*)&Xs[(mg*4+mi)*16 + c][kk*32 + q*8];
      #pragma unroll
      for (int ni = 0; ni < 4; ++ni)
        bfr[ni] = *(const bf16x8*)&Ws[(ng*4+ni)*16 + c][kk*32 + q*8];
      #pragma unroll
      for (int mi = 0; mi < 4; ++mi)
        #pragma unroll
        for (int ni = 0; ni < 4; ++ni)
          acc1[mi][ni] = __builtin_amdgcn_mfma_f32_16x16x32_bf16(af[mi], bfr[ni], acc1[mi][ni], 0, 0, 0);
    }
  }
  __syncthreads();     // done reading Xs/Ws (Ys aliases them)

  // relu + C-layout (col=lane&15, row=(lane>>4)*4+reg) -> Ys[row][col] bf16
  #pragma unroll
  for (int mi = 0; mi < 4; ++mi)
    #pragma unroll
    for (int ni = 0; ni < 4; ++ni)
      #pragma unroll
      for (int reg = 0; reg < 4; ++reg)
        Ys[(mg*4+mi)*16 + q*4 + reg][(ng*4+ni)*16 + c] =
            (short)f2bf(fmaxf(acc1[mi][ni][reg], 0.f));
  __syncthreads();

  // ---- stage 2: gi = Y @ Wih^T + bih ----
  bf16x8 Af[2][4];
  #pragma unroll
  for (int mi = 0; mi < 2; ++mi)
    #pragma unroll
    for (int kt = 0; kt < 4; ++kt)
      Af[mi][kt] = *(const bf16x8*)&Ys[(w*2+mi)*16 + c][kt*32 + q*8];

  float bihv[24];
  #pragma unroll
  for (int nt = 0; nt < 24; ++nt)
    bihv[nt] = mbih[g*384 + nt*16 + c];

  short* gslab = gi + (((size_t)pt*64 + rb)*32)*384*4;   // bf16 [m][col][s4]
  #pragma unroll 1
  for (int cn = 0; cn < 6; ++cn) {
    f32x4 acc2[2][4];
    #pragma unroll
    for (int mi = 0; mi < 2; ++mi)
      #pragma unroll
      for (int ni = 0; ni < 4; ++ni) acc2[mi][ni] = (f32x4){0.f,0.f,0.f,0.f};
    #pragma unroll
    for (int ni = 0; ni < 4; ++ni) {
      int n = (cn*4 + ni)*16 + c;
      const short* bp_ = wihb + ((size_t)g*384 + n)*128 + q*8;
      #pragma unroll
      for (int kt = 0; kt < 4; ++kt) {
        bf16x8 bfr = *(const bf16x8*)(bp_ + kt*32);
        #pragma unroll
        for (int mi = 0; mi < 2; ++mi)
          acc2[mi][ni] = __builtin_amdgcn_mfma_f32_16x16x32_bf16(Af[mi][kt], bfr, acc2[mi][ni], 0, 0, 0);
      }
    }
    __syncthreads();
    #pragma unroll
    for (int mi = 0; mi < 2; ++mi)
      #pragma unroll
      for (int ni = 0; ni < 4; ++ni) {
        float bia = bihv[cn*4+ni];
        #pragma unroll
        for (int reg = 0; reg < 4; ++reg)
          giS[(w*2+mi)*16 + q*4 + reg][ni*16 + c] = acc2[mi][ni][reg] + bia;
      }
    __syncthreads();
    #pragma unroll
    for (int k = 0; k < 8; ++k) {
      int o4 = tid + k*256;            // 0..2047
      int m = o4 >> 6, colL = o4 & 63;
      bf16x4 v;
      v[0] = (short)f2bf(giS[m][colL]);
      v[1] = (short)f2bf(giS[32+m][colL]);
      v[2] = (short)f2bf(giS[64+m][colL]);
      v[3] = (short)f2bf(giS[96+m][colL]);
      *(bf16x4*)&gslab[((size_t)m*384 + cn*64 + colL)*4] = v;
    }
  }
}

// =====================================================================
// monitor-level GRU v8.1 — verified round 3, unchanged.
// =====================================================================
__global__ __launch_bounds__(512, 2) void k_mgru(
    const short* __restrict__ gi, const float* __restrict__ mWhh,
    const float* __restrict__ mbhh, float* __restrict__ last)
{
  const int run  = blockIdx.x >> 4;     // 0..7
  const int pair = blockIdx.x & 15;     // 0..15 (16 seqs per block)
  const int g = (run % 4 == 0) ? (run / 4) : (run % 4 + 1);
  const int tid = threadIdx.x;
  const int w = tid >> 6;               // wave 0..7 = hidden slice
  const int lane = tid & 63;
  const int c = lane & 15, q = lane >> 4;
  const int j = w*16 + c;               // hidden index 0..127

  __shared__ short hb[2][4][16][40];    // [buf][kt][seq][kk+pad] bf16, 10240 B

  for (int idx = tid; idx < 2*4*16*40; idx += 512)
    ((short*)hb)[idx] = 0;

  // ---- B fragments in registers: Whh rows for cols gate*128+j ----
  bf16x8 bfrag[3][4];
  #pragma unroll
  for (int gate = 0; gate < 3; ++gate) {
    const float* wp = mWhh + ((size_t)g*384 + gate*128 + j)*128 + q*8;
    #pragma unroll
    for (int kt = 0; kt < 4; ++kt) {
      float4 lo = *(const float4*)(wp + kt*32);
      float4 hi = *(const float4*)(wp + kt*32 + 4);
      bf16x8 t;
      t[0]=(short)f2bf(lo.x); t[1]=(short)f2bf(lo.y); t[2]=(short)f2bf(lo.z); t[3]=(short)f2bf(lo.w);
      t[4]=(short)f2bf(hi.x); t[5]=(short)f2bf(hi.y); t[6]=(short)f2bf(hi.z); t[7]=(short)f2bf(hi.w);
      bfrag[gate][kt] = t;
    }
  }
  const float bh0 = mbhh[g*384 +       j];
  const float bh1 = mbhh[g*384 + 128 + j];
  const float bh2 = mbhh[g*384 + 256 + j];

  const short* gib = gi + ((size_t)((run*64 + pair*4 + q)*32))*1536;
  const short* gpl = gib + j*4;         // lane base; gate offset = 1024 B

  float hf[4] = {0.f,0.f,0.f,0.f};
  const int ktw = w >> 1;               // j>>5
  const int kkw = (w & 1)*16 + c;       // j&31

  // 3-deep rotating prefetch buffers (3 gates x 8B each)
  u32x2 g0[3], g1[3], g2[3];
  GLD(g0[0], gpl,        "0");
  GLD(g0[1], gpl,        "1024");
  GLD(g0[2], gpl,        "2048");
  GLD(g1[0], gpl + 1536, "0");
  GLD(g1[1], gpl + 1536, "1024");
  GLD(g1[2], gpl + 1536, "2048");
  const short* gpn = gpl + 2*1536;      // next issue pointer (step m+2)

  ldsbar();   // hb zero-init visible; prefetches stay in flight

  auto step = [&](int m, u32x2 (&gcur)[3], u32x2 (&giss)[3], int wsel) {
    const int cur = m & 1, nxt = cur ^ 1;
    bf16x8 a[4];
    #pragma unroll
    for (int kt = 0; kt < 4; ++kt)
      a[kt] = *(const bf16x8*)&hb[cur][kt][c][q*8];
    f32x4 acc[3];
    #pragma unroll
    for (int gate = 0; gate < 3; ++gate) {
      f32x4 t = {0.f,0.f,0.f,0.f};
      #pragma unroll
      for (int kt = 0; kt < 4; ++kt)
        t = __builtin_amdgcn_mfma_f32_16x16x32_bf16(a[kt], bfrag[gate][kt], t, 0, 0, 0);
      acc[gate] = t;
    }
    if (wsel == 0) {
      GLD(giss[0], gpn, "0");
      GLD(giss[1], gpn, "1024");
      GLD(giss[2], gpn, "2048");
      gpn += 1536;
    }
    if (wsel == 0)      asm volatile("s_waitcnt vmcnt(6)" ::: "memory");
    else if (wsel == 1) asm volatile("s_waitcnt vmcnt(3)" ::: "memory");
    else                asm volatile("s_waitcnt vmcnt(0)" ::: "memory");
    __builtin_amdgcn_sched_barrier(0);
    float ga[3][4];
    #pragma unroll
    for (int gate = 0; gate < 3; ++gate) {
      ga[gate][0] = u2f(gcur[gate].x << 16);
      ga[gate][1] = u2f(gcur[gate].x & 0xffff0000u);
      ga[gate][2] = u2f(gcur[gate].y << 16);
      ga[gate][3] = u2f(gcur[gate].y & 0xffff0000u);
    }
    #pragma unroll
    for (int reg = 0; reg < 4; ++reg) {
      float rr = fsig(acc[0][reg] + bh0 + ga[0][reg]);
      float zz = fsig(acc[1][reg] + bh1 + ga[1][reg]);
      float nn = ftanh(ga[2][reg] + rr*(acc[2][reg] + bh2));
      float hnew = (1.f - zz)*nn + zz*hf[reg];
      hf[reg] = hnew;
      hb[nxt][ktw][q*4 + reg][kkw] = (short)f2bf(hnew);
    }
    ldsbar();
  };

  #pragma unroll 1
  for (int mb = 0; mb < 30; mb += 6) {
    step(mb+0, g0, g2, 0);
    step(mb+1, g1, g0, 0);
    step(mb+2, g2, g1, 0);
    step(mb+3, g0, g2, 0);
    step(mb+4, g1, g0, 0);
    step(mb+5, g2, g1, 0);
  }
  step(30, g0, g2, 1);
  step(31, g1, g0, 2);

  #pragma unroll
  for (int reg = 0; reg < 4; ++reg)
    last[((size_t)run*NSEQ + pair*16 + q*4 + reg)*D_ + j] = hf[reg];
}

// =====================================================================
// visit-level GRU + head FUSED (k_vgh) — THIS ROUND.
// 112 blocks = 7 concat-segments x 16 batches, 768 threads.
// Pair-segments (cond/proc/drug) run both vgru recurrences concurrently
// in thread-halves (384 thr each, full 128-dot, w[128] regs, gi bf16 in
// LDS). Then each block computes its 128-dim slice of relu(pe)@Wp^T and
// atomicAdds 600 partials into out (bias pre-init by k_prepvis tail).
// Removes the k_head dispatch + the vh global round-trip.
// =====================================================================
__global__ __launch_bounds__(768, 1) void k_vgh(
    const float* __restrict__ last, const float* __restrict__ xe,
    const float* __restrict__ wihTv, const float* __restrict__ vbih,
    const float* __restrict__ vWhh, const float* __restrict__ vbhh,
    const float* __restrict__ Wp, float* __restrict__ out)
{
  const int s = blockIdx.x >> 4;        // segment 0..6
  const int b = blockIdx.x & 15;        // batch
  const int tid = threadIdx.x;
  const int a1 = s + ((s >= 5) ? 3 : 0);             // {0,1,2,3,4,8,9}
  const bool haspair = (s >= 1 && s <= 3);
  const int a2 = haspair ? (s + 4) : -1;             // {-,5,6,7,-,-,-}
  const int half = (tid >= 384) ? 1 : 0;
  const int j = tid - half*384;                      // 0..383
  const int run = half ? a2 : a1;
  const bool act = (run >= 0);
  const int vidx = act ? ((run < 4) ? 0 : (run < 8) ? 1 : (run - 6)) : 0;

  __shared__ float Xs[2][16][128];                   // 16 KB
  __shared__ short giLb[2][16*384];                  // 24 KB (bf16 gi)
  __shared__ __align__(16) float hsv[2][128];        // 1 KB
  __shared__ float gh[2][384];                       // 3 KB

  if (act) {
    const float* X = (run < 8) ? (last + ((size_t)run*NSEQ + b*16)*D_)
                               : (xe + ((size_t)(run-8)*NSEQ + b*16)*D_);
    for (int idx = j; idx < 2048; idx += 384)
      ((float*)Xs[half])[idx] = X[idx];
  }
  if (tid < 256) hsv[tid>>7][tid&127] = 0.f;
  __syncthreads();

  // ---- gi precompute (bf16 into LDS), 2 passes of 8 visits ----
  if (act) {
    const float bias = vbih[vidx*384 + j];
    const float* W = wihTv + vidx*49152 + j;
    #pragma unroll 1
    for (int vh2 = 0; vh2 < 2; ++vh2) {
      float accv[8];
      #pragma unroll
      for (int v = 0; v < 8; ++v) accv[v] = bias;
      #pragma unroll 4
      for (int k = 0; k < 128; ++k) {
        float wv = W[k*384];
        #pragma unroll
        for (int v = 0; v < 8; ++v) accv[v] += Xs[half][vh2*8 + v][k] * wv;
      }
      #pragma unroll
      for (int v = 0; v < 8; ++v)
        giLb[half][(vh2*8 + v)*384 + j] = (short)f2bf(accv[v]);
    }
  }

  // ---- recurrence weights: full 128-row per thread ----
  float w[128];
  float bj = 0.f;
  if (act) {
    const float4* wrow = (const float4*)(vWhh + ((size_t)vidx*384 + j)*128);
    #pragma unroll
    for (int k4 = 0; k4 < 32; ++k4) {
      float4 t4 = wrow[k4];
      w[4*k4] = t4.x; w[4*k4+1] = t4.y; w[4*k4+2] = t4.z; w[4*k4+3] = t4.w;
    }
    bj = vbhh[vidx*384 + j];
  }
  __syncthreads();

  #pragma unroll 1
  for (int v = 0; v < 16; ++v) {
    if (act) {
      const float4* h4 = (const float4*)hsv[half];
      float p0 = 0.f, p1 = 0.f;
      #pragma unroll
      for (int k4 = 0; k4 < 16; ++k4) {
        float4 u0 = h4[k4], u1 = h4[k4+16];
        p0 += w[4*k4   ]*u0.x + w[4*k4+1 ]*u0.y + w[4*k4+2 ]*u0.z + w[4*k4+3 ]*u0.w;
        p1 += w[4*k4+64]*u1.x + w[4*k4+65]*u1.y + w[4*k4+66]*u1.z + w[4*k4+67]*u1.w;
      }
      gh[half][j] = bj + ((j < 256) ? bf2f(giLb[half][v*384 + j]) : 0.f) + p0 + p1;
    }
    __syncthreads();
    if (tid < 256) {
      const int h2 = tid >> 7, jj = tid & 127;
      if (h2 == 0 || haspair) {
        float r = fsig(gh[h2][jj]);
        float z = fsig(gh[h2][jj+128]);
        float gin = bf2f(giLb[h2][v*384 + 256 + jj]);
        float n = ftanh(gin + r*gh[h2][jj+256]);
        hsv[h2][jj] = (1.f - z)*n + z*hsv[h2][jj];
      }
    }
    __syncthreads();
  }

  // ---- head partial: relu(h1 + h2) . Wp[:, s*128 .. +127] ----
  if (tid < OUT_) {
    const int o = tid;
    const float* wr = Wp + (size_t)o*896 + s*128;
    float acc = 0.f;
    #pragma unroll
    for (int d4 = 0; d4 < 32; ++d4) {
      float4 ww  = *(const float4*)(wr + d4*4);
      float4 h0v = *(const float4*)&hsv[0][d4*4];
      float4 h1v = *(const float4*)&hsv[1][d4*4];
      acc += fmaxf(h0v.x + h1v.x, 0.f)*ww.x + fmaxf(h0v.y + h1v.y, 0.f)*ww.y
           + fmaxf(h0v.z + h1v.z, 0.f)*ww.z + fmaxf(h0v.w + h1v.w, 0.f)*ww.w;
    }
    atomicAdd(&out[b*OUT_ + o], acc);
  }
}

// =====================================================================
extern "C" void kernel_launch(void* const* d_in, const int* in_sizes, int n_in,
                              void* d_out, int out_size, void* d_ws, size_t ws_size,
                              hipStream_t stream)
{
  (void)in_sizes; (void)n_in; (void)out_size; (void)ws_size;
  const int*   cc   = (const int*)  d_in[0];
  const int*   cp   = (const int*)  d_in[1];
  const int*   cd   = (const int*)  d_in[2];
  const int*   cli  = (const int*)  d_in[3];
  const int*   clv  = (const int*)  d_in[4];
  const int*   cii  = (const int*)  d_in[5];
  const int*   civ  = (const int*)  d_in[6];
  const float* wgt  = (const float*)d_in[7];
  const float* age  = (const float*)d_in[8];
  const float* ec   = (const float*)d_in[9];
  const float* ep   = (const float*)d_in[10];
  const float* ed   = (const float*)d_in[11];
  const float* eli  = (const float*)d_in[12];
  const float* elv  = (const float*)d_in[13];
  const float* eii  = (const float*)d_in[14];
  const float* eiv  = (const float*)d_in[15];
  const float* mWih = (const float*)d_in[16];
  const float* mWhh = (const float*)d_in[17];
  const float* mbih = (const float*)d_in[18];
  const float* mbhh = (const float*)d_in[19];
  const float* vWih = (const float*)d_in[20];
  const float* vWhh = (const float*)d_in[21];
  const float* vbih = (const float*)d_in[22];
  const float* vbhh = (const float*)d_in[23];
  const float* Wself= (const float*)d_in[24];
  const float* Wmsg = (const float*)d_in[25];
  const float* fwW  = (const float*)d_in[26];
  const float* fwB  = (const float*)d_in[27];
  const float* faW  = (const float*)d_in[28];
  const float* faB  = (const float*)d_in[29];
  const float* Wp   = (const float*)d_in[30];
  const float* bp   = (const float*)d_in[31];
  float* out = (float*)d_out;
  float* ws  = (float*)d_ws;

  float* vis   = ws + OFF_VIS;
  short* visb  = (short*)(ws + OFF_VISB);
  short* monb  = (short*)(ws + OFF_MONB);
  short* totb  = (short*)(ws + OFF_TOTB);
  short* w12t  = (short*)(ws + OFF_W12T);
  short* wihb  = (short*)(ws + OFF_WIHB);
  float* wihTv = ws + OFF_WIHTV;
  float* xe    = ws + OFF_XE;
  short* gi    = (short*)(ws + OFF_GI);
  float* last  = ws + OFF_LAST;

  k_prepvis<<<3430, 256, 0, stream>>>(Wself, Wmsg, mWih, vWih, wgt, age,
                                      fwW, fwB, faW, faB,
                                      cc, cp, cd, ec, ep, ed, bp,
                                      w12t, wihb, wihTv, xe, vis, visb, out);
  k_mon <<<16384, 128, 0, stream>>>(cli, clv, cii, civ, eli, elv, eii, eiv,
                                    vis, monb, totb);
  k_gg  <<<512, 256, 0, stream>>>(monb, totb, visb, w12t, wihb, mbih, gi);
  k_mgru<<<128, 512, 0, stream>>>(gi, mWhh, mbhh, last);
  k_vgh <<<112, 768, 0, stream>>>(last, xe, wihTv, vbih, vWhh, vbhh, Wp, out);
}

// Round 6
// 251.967 us; speedup vs baseline: 1.6660x; 1.6660x over previous
//
#include <hip/hip_runtime.h>
#include <math.h>

#define B_   16
#define V_   16
#define C_   64
#define M_   32
#define CM_  16
#define D_   128
#define OUT_ 600
#define NSEQ 256      // B*V
#define NROW 8192     // B*V*M

typedef __attribute__((ext_vector_type(8))) short bf16x8;
typedef __attribute__((ext_vector_type(4))) short bf16x4;
typedef __attribute__((ext_vector_type(4))) float f32x4;

__device__ __forceinline__ unsigned short f2bf(float x) {
  union { float f; unsigned u; } v; v.f = x;
  unsigned r = v.u + 0x7fff + ((v.u >> 16) & 1);   // RNE
  return (unsigned short)(r >> 16);
}
__device__ __forceinline__ float bf2f(short s) {
  union { unsigned u; float f; } v;
  v.u = ((unsigned)(unsigned short)s) << 16;
  return v.f;
}
// fast sigmoid / tanh: native v_exp + v_rcp (~5 inst), saturate correctly
__device__ __forceinline__ float fsig(float x)  { return __fdividef(1.f, 1.f + __expf(-x)); }
__device__ __forceinline__ float ftanh(float x) { return 1.f - 2.f*__fdividef(1.f, __expf(2.f*x) + 1.f); }

// LDS-only barrier: drains LDS ops for cross-wave visibility but does NOT
// drain vmcnt — in-flight global prefetch loads survive the barrier.
__device__ __forceinline__ void ldsbar() {
  asm volatile("s_waitcnt lgkmcnt(0)" ::: "memory");
  __builtin_amdgcn_s_barrier();
  asm volatile("" ::: "memory");
}

// ---- workspace layout (float units; bf16 arrays are short* views) ----
constexpr int OFF_VIS   = 0;                               // fp32 [3][256][128]
constexpr int OFF_VISB  = 98304;                           // bf16 [3][256][128]
constexpr int OFF_MONB  = 147456;                          // bf16 [2][8192][128]
constexpr int OFF_TOTB  = 1196032;                         // bf16 [2][8192][128]
constexpr int OFF_W12T  = 2244608;                         // bf16 [8][128n][256k]
constexpr int OFF_WIHB  = 2375680;                         // bf16 [5][384n][128k]
constexpr int OFF_WIHTV = 2498560;                         // fp32 [4][128][384]
constexpr int OFF_XE    = 2695168;                         // fp32 [2][256][128]
constexpr int OFF_LAST  = 27926528;                        // fp32 [8][256][128]
constexpr int OFF_VH    = 29171712;                        // fp32 [10][16][128]

// =====================================================================
// prep+vis merged — verified round-3 form (reverted).
// =====================================================================
__global__ __launch_bounds__(256) void k_prepvis(
    const float* __restrict__ Wself, const float* __restrict__ Wmsg,
    const float* __restrict__ mWih,  const float* __restrict__ vWih,
    const float* __restrict__ wgt,   const float* __restrict__ age,
    const float* __restrict__ fwW,   const float* __restrict__ fwB,
    const float* __restrict__ faW,   const float* __restrict__ faB,
    const int* __restrict__ cc, const int* __restrict__ cp, const int* __restrict__ cd,
    const float* __restrict__ ec, const float* __restrict__ ep, const float* __restrict__ ed,
    short* __restrict__ w12t, short* __restrict__ wihb,
    float* __restrict__ wihTv, float* __restrict__ xe,
    float* __restrict__ vis, short* __restrict__ visb)
{
  int bx = blockIdx.x, tid = threadIdx.x;
  if (bx < 1024) {                      // w12t[pt][n][k] = bf16 combined
    int lin = bx*256 + tid;             // < 262144
    int pt = lin >> 15, rem = lin & 32767;
    int n = rem >> 8, k = rem & 255;
    float v;
    if (k < 128) v = Wself[pt*16384 + k*128 + n] - Wmsg[pt*16384 + k*128 + n]*(1.f/3.f);
    else         v = Wmsg[pt*16384 + (k-128)*128 + n]*(1.f/3.f);
    w12t[lin] = (short)f2bf(v);
  } else if (bx < 1984) {               // wihb = bf16(mWih) elementwise
    int lin = (bx-1024)*256 + tid;      // < 245760
    wihb[lin] = (short)f2bf(mWih[lin]);
  } else if (bx < 2752) {               // vgru Wih transpose fp32
    int lin = (bx-1984)*256 + tid;      // < 196608
    int g = lin / 49152, rem2 = lin % 49152;
    int k = rem2 / 384, j = rem2 % 384;
    wihTv[lin] = vWih[g*49152 + j*128 + k];
  } else if (bx < 3008) {               // xe for weight / age
    int lin = (bx-2752)*256 + tid;      // < 65536
    int which = lin >> 15, rem2 = lin & 32767;
    int n = rem2 >> 7, d = rem2 & 127;
    float x  = which ? age[n] : wgt[n];
    float Wv = which ? faW[d] : fwW[d];
    float bb = which ? faB[d] : fwB[d];
    xe[lin] = (x != 0.0f) ? (x*Wv + bb) : 0.0f;
  } else {                              // visit-event sum pools
    int idx = (bx-3008)*256 + tid;      // < 98304
    int type = idx >> 15;
    int r = idx & 32767;
    int bv = r >> 7, d = r & 127;
    const int*   codes = (type==0) ? cc : (type==1) ? cp : cd;
    const float* emb   = (type==0) ? ec : (type==1) ? ep : ed;
    float acc = 0.f;
    for (int c = 0; c < C_; ++c) {
      int code = codes[bv*C_ + c];
      acc += emb[code*D_ + d];
    }
    vis [(type*NSEQ + bv)*D_ + d] = acc;
    visb[(type*NSEQ + bv)*D_ + d] = (short)f2bf(acc);
  }
}

// =====================================================================
// monitor-event pools — unchanged (verified).
// =====================================================================
__global__ __launch_bounds__(128) void k_mon(
    const int* __restrict__ cli, const int* __restrict__ clv,
    const int* __restrict__ cii, const int* __restrict__ civ,
    const float* __restrict__ eli, const float* __restrict__ elv,
    const float* __restrict__ eii, const float* __restrict__ eiv,
    const float* __restrict__ vis,
    short* __restrict__ monb, short* __restrict__ totb)
{
  int p   = blockIdx.x >> 13;
  int bvm = blockIdx.x & 8191;
  int d   = threadIdx.x;
  const int* ci = p ? cii : cli;  const int* cv = p ? civ : clv;
  const float* ei = p ? eii : eli; const float* ev = p ? eiv : elv;
  float acc = 0.f;
  #pragma unroll
  for (int c = 0; c < CM_; ++c) {
    int iv = ci[bvm*CM_ + c];
    int vv = cv[bvm*CM_ + c];
    acc += ei[iv*D_ + d] * ev[vv*D_ + d];
  }
  int bv = bvm >> 5;
  float vsum = vis[bv*D_ + d] + vis[(NSEQ + bv)*D_ + d] + vis[(2*NSEQ + bv)*D_ + d];
  monb[(p*NROW + bvm)*D_ + d] = (short)f2bf(acc);
  totb[(p*NROW + bvm)*D_ + d] = (short)f2bf(acc + vsum);
}

// =====================================================================
// FUSED GNN+GI+monitor-GRU (k_ggru) — THIS ROUND.
// Replaces k_gg + k_mgru: gi (50 MB intermediate, 61 MB write + 28 MB
// re-fetch) never touches HBM. Per block (run, batch b) = 16 seqs.
// Per step m:
//   X(m) = [feat|tot] 16 rows x 256 cols bf16, reg-staged into
//   XOR-swizzled LDS one step ahead;
//   stage1: Y = relu(X @ W12^T)        (8 MFMA/wave, Ys bf16 relay)
//   stage2/3: gate pre-acts = Y@Wih^T + h@Whh^T, wave w owns gate-cols
//   {gate*128 + w*16+c} with REGISTER B-frags -> lane-local activation
//   (identical mapping to verified v8).
// =====================================================================
__global__ __launch_bounds__(512, 1) void k_ggru(
    const short* __restrict__ monb, const short* __restrict__ totb,
    const short* __restrict__ visb, const short* __restrict__ w12t,
    const short* __restrict__ wihb, const float* __restrict__ mWhh,
    const float* __restrict__ mbih, const float* __restrict__ mbhh,
    float* __restrict__ last)
{
  const int run  = blockIdx.x >> 4;     // 0..7
  const int pair = blockIdx.x & 15;     // batch b
  const int p = run >> 2, t = run & 3;
  const int g = (run % 4 == 0) ? (run / 4) : (run % 4 + 1);
  const int tid = threadIdx.x;
  const int w = tid >> 6;               // wave 0..7 = hidden slice
  const int lane = tid & 63;
  const int c = lane & 15, q = lane >> 4;
  const int j = w*16 + c;               // hidden index 0..127

  __shared__ short hb[2][4][16][40];            // 10240 B (v8-verified layout)
  __shared__ __align__(16) short Ys[16][136];   // 4352 B
  __shared__ __align__(16) short Xl[2][4096];   // 16384 B, XOR-swizzled rows

  for (int idx = tid; idx < 2*4*16*40; idx += 512)
    ((short*)hb)[idx] = 0;

  // ---- stage1 B-frags: w12t[run][n=w*16+c][k], K=256 -> 8 frags ----
  bf16x8 bW12[8];
  #pragma unroll
  for (int kt = 0; kt < 8; ++kt)
    bW12[kt] = *(const bf16x8*)(w12t + (size_t)run*32768 + (size_t)(w*16+c)*256 + kt*32 + q*8);

  // ---- stage2 B-frags: wihb rows gate*128+j ----
  bf16x8 bWih[3][4];
  #pragma unroll
  for (int gate = 0; gate < 3; ++gate)
    #pragma unroll
    for (int kt = 0; kt < 4; ++kt)
      bWih[gate][kt] = *(const bf16x8*)(wihb + ((size_t)g*384 + gate*128 + j)*128 + kt*32 + q*8);

  // ---- stage3 B-frags: mWhh rows gate*128+j (fp32 -> bf16) ----
  bf16x8 bWhh[3][4];
  #pragma unroll
  for (int gate = 0; gate < 3; ++gate) {
    const float* wp = mWhh + ((size_t)g*384 + gate*128 + j)*128 + q*8;
    #pragma unroll
    for (int kt = 0; kt < 4; ++kt) {
      float4 lo = *(const float4*)(wp + kt*32);
      float4 hi = *(const float4*)(wp + kt*32 + 4);
      bf16x8 tt;
      tt[0]=(short)f2bf(lo.x); tt[1]=(short)f2bf(lo.y); tt[2]=(short)f2bf(lo.z); tt[3]=(short)f2bf(lo.w);
      tt[4]=(short)f2bf(hi.x); tt[5]=(short)f2bf(hi.y); tt[6]=(short)f2bf(hi.z); tt[7]=(short)f2bf(hi.w);
      bWhh[gate][kt] = tt;
    }
  }
  const float bs0 = mbih[g*384 +       j] + mbhh[g*384 +       j];
  const float bs1 = mbih[g*384 + 128 + j] + mbhh[g*384 + 128 + j];
  const float bi2 = mbih[g*384 + 256 + j];
  const float bh2 = mbhh[g*384 + 256 + j];

  // ---- X staging mapping: thread (r = tid>>5, u = tid&31) ----
  const int xr_ = tid >> 5, xu = tid & 31;
  const int bv = pair*16 + xr_;
  const short* fsrc;
  int fstride;                                   // shorts per step
  if (xu < 16) {
    if (t == 0) { fsrc = monb + ((size_t)p*NROW + (size_t)bv*32)*128 + xu*8; fstride = 128; }
    else        { fsrc = visb + ((size_t)(t-1)*NSEQ + bv)*128 + xu*8;        fstride = 0;   }
  } else {
    fsrc = totb + ((size_t)p*NROW + (size_t)bv*32)*128 + (xu-16)*8;          fstride = 128;
  }
  const int xdofs = xr_*256 + (((xu*16) ^ ((xr_&7)<<4)) >> 1);   // shorts
  short* xdst0 = &Xl[0][xdofs];
  short* xdst1 = &Xl[1][xdofs];

  // prologue: X(0) -> Xl[0]
  {
    bf16x8 x0 = *(const bf16x8*)fsrc;
    *(bf16x8*)xdst0 = x0;
  }
  float hf[4] = {0.f,0.f,0.f,0.f};
  const int ktw = w >> 1;               // j>>5
  const int kkw = (w & 1)*16 + c;       // j&31
  ldsbar();   // hb zero + X(0) visible

  #pragma unroll 1
  for (int m = 0; m < 32; ++m) {
    const int cur = m & 1;
    // issue X(m+1) global load early (latency hidden under this step)
    bf16x8 xnext;
    if (m < 31) xnext = *(const bf16x8*)(fsrc + (size_t)(m+1)*fstride);

    // ---- stage1: Y = relu(X @ W12^T), wave's 16 cols ----
    const char* xbase = (const char*)&Xl[cur][0];
    f32x4 accY = (f32x4){0.f,0.f,0.f,0.f};
    #pragma unroll
    for (int kt = 0; kt < 8; ++kt) {
      bf16x8 aX = *(const bf16x8*)(xbase + c*512 + ((kt*64 + q*16) ^ ((c&7)<<4)));
      accY = __builtin_amdgcn_mfma_f32_16x16x32_bf16(aX, bW12[kt], accY, 0, 0, 0);
    }
    #pragma unroll
    for (int reg = 0; reg < 4; ++reg)
      Ys[q*4 + reg][w*16 + c] = (short)f2bf(fmaxf(accY[reg], 0.f));
    ldsbar();   // B1: Ys ready (X(m+1) load stays in flight)

    // ---- stage2+3: gate pre-acts for this wave's 16 cols ----
    bf16x8 ah[4], a2[4];
    #pragma unroll
    for (int kt = 0; kt < 4; ++kt) {
      ah[kt] = *(const bf16x8*)&hb[cur][kt][c][q*8];
      a2[kt] = *(const bf16x8*)&Ys[c][kt*32 + q*8];
    }
    f32x4 acc0 = (f32x4){0.f,0.f,0.f,0.f};
    f32x4 acc1 = (f32x4){0.f,0.f,0.f,0.f};
    f32x4 aG2  = (f32x4){0.f,0.f,0.f,0.f};
    f32x4 aH2  = (f32x4){0.f,0.f,0.f,0.f};
    #pragma unroll
    for (int kt = 0; kt < 4; ++kt) {
      acc0 = __builtin_amdgcn_mfma_f32_16x16x32_bf16(ah[kt], bWhh[0][kt], acc0, 0, 0, 0);
      acc1 = __builtin_amdgcn_mfma_f32_16x16x32_bf16(ah[kt], bWhh[1][kt], acc1, 0, 0, 0);
      aH2  = __builtin_amdgcn_mfma_f32_16x16x32_bf16(ah[kt], bWhh[2][kt], aH2,  0, 0, 0);
    }
    #pragma unroll
    for (int kt = 0; kt < 4; ++kt) {
      acc0 = __builtin_amdgcn_mfma_f32_16x16x32_bf16(a2[kt], bWih[0][kt], acc0, 0, 0, 0);
      acc1 = __builtin_amdgcn_mfma_f32_16x16x32_bf16(a2[kt], bWih[1][kt], acc1, 0, 0, 0);
      aG2  = __builtin_amdgcn_mfma_f32_16x16x32_bf16(a2[kt], bWih[2][kt], aG2,  0, 0, 0);
    }

    // write X(m+1) into the other buffer (reads of it finished in m-1)
    if (m < 31) *(bf16x8*)(cur ? xdst0 : xdst1) = xnext;

    // ---- lane-local GRU activation: (seq = q*4+reg, this j) ----
    const int nxt = cur ^ 1;
    #pragma unroll
    for (int reg = 0; reg < 4; ++reg) {
      float rr = fsig(acc0[reg] + bs0);
      float zz = fsig(acc1[reg] + bs1);
      float nn = ftanh(aG2[reg] + bi2 + rr*(aH2[reg] + bh2));
      float hnew = (1.f - zz)*nn + zz*hf[reg];
      hf[reg] = hnew;
      hb[nxt][ktw][q*4 + reg][kkw] = (short)f2bf(hnew);
    }
    ldsbar();   // B2: hb(nxt) + X(m+1) visible for step m+1
  }

  #pragma unroll
  for (int reg = 0; reg < 4; ++reg)
    last[((size_t)run*NSEQ + pair*16 + q*4 + reg)*D_ + j] = hf[reg];
}

// =====================================================================
// visit-level GRU v3 (vgi fused) — verified round-3 form (reverted).
// =====================================================================
__global__ __launch_bounds__(768) void k_vgru(
    const float* __restrict__ last, const float* __restrict__ xe,
    const float* __restrict__ wihTv, const float* __restrict__ vbih,
    const float* __restrict__ vWhh, const float* __restrict__ vbhh,
    float* __restrict__ vh)
{
  int run = blockIdx.x >> 4, b = blockIdx.x & 15;
  int tid = threadIdx.x;
  int vidx = (run < 4) ? 0 : (run < 8) ? 1 : (run - 6);

  __shared__ float Xs[16][128];          // 8 KB
  __shared__ float giL[16*384];          // 24 KB
  __shared__ __align__(16) float hsv[128];
  __shared__ float gh[384];

  const float* X = (run < 8) ? (last + ((size_t)run*NSEQ + b*16)*D_)
                             : (xe + ((size_t)(run-8)*NSEQ + b*16)*D_);
  for (int idx = tid; idx < 2048; idx += 768)
    ((float*)Xs)[idx] = X[idx];
  if (tid < 128) hsv[tid] = 0.f;
  __syncthreads();

  // ---- gi precompute into LDS: thread (half, j) does 8 visits ----
  {
    int half = (tid >= 384) ? 1 : 0;
    int j = tid - half*384;
    float accv[8];
    float bias = vbih[vidx*384 + j];
    #pragma unroll
    for (int s = 0; s < 8; ++s) accv[s] = bias;
    const float* W = wihTv + vidx*49152 + j;
    #pragma unroll 4
    for (int k = 0; k < 128; ++k) {
      float wv = W[k*384];
      #pragma unroll
      for (int s = 0; s < 8; ++s) accv[s] += Xs[half*8 + s][k] * wv;
    }
    #pragma unroll
    for (int s = 0; s < 8; ++s)
      giL[(half*8 + s)*384 + j] = accv[s];
  }

  // ---- recurrence weights (pair-split, w[64]/thread, no spill) ----
  int j = tid >> 1, kh = tid & 1;
  float w[64];
  const float4* wrow = (const float4*)(vWhh + (vidx*384 + j)*128 + kh*64);
  #pragma unroll
  for (int k4 = 0; k4 < 16; ++k4) {
    float4 t4 = wrow[k4];
    w[4*k4] = t4.x; w[4*k4+1] = t4.y; w[4*k4+2] = t4.z; w[4*k4+3] = t4.w;
  }
  float bj = vbhh[vidx*384 + j];
  __syncthreads();

  #pragma unroll 1
  for (int v = 0; v < 16; ++v) {
    const float4* h4 = (const float4*)(hsv + kh*64);
    float p0 = 0.f, p1 = 0.f;
    #pragma unroll
    for (int k4 = 0; k4 < 8; ++k4) {
      float4 u0 = h4[k4], u1 = h4[k4+8];
      p0 += w[4*k4   ]*u0.x + w[4*k4+1 ]*u0.y + w[4*k4+2 ]*u0.z + w[4*k4+3 ]*u0.w;
      p1 += w[4*k4+32]*u1.x + w[4*k4+33]*u1.y + w[4*k4+34]*u1.z + w[4*k4+35]*u1.w;
    }
    float part = p0 + p1;
    part += __shfl_xor(part, 1);
    if (kh == 0) gh[j] = bj + ((j < 256) ? giL[v*384 + j] : 0.f) + part;
    __syncthreads();
    if (tid < 128) {
      float r = fsig(gh[tid]);
      float z = fsig(gh[tid+128]);
      float gin = giL[v*384 + 256 + tid];
      float n = ftanh(gin + r*gh[tid+256]);
      hsv[tid] = (1.f - z)*n + z*hsv[tid];
    }
    __syncthreads();
  }
  if (tid < 128) vh[(run*16 + b)*D_ + tid] = hsv[tid];
}

// =====================================================================
// head v4 (pe fused) — verified round-3 form (reverted).
// =====================================================================
__global__ __launch_bounds__(256) void k_head(
    const float* __restrict__ vh, const float* __restrict__ Wp,
    const float* __restrict__ bp, float* __restrict__ out)
{
  const int o = blockIdx.x;
  const int tid = threadIdx.x;
  const int b = tid & 15, kc = tid >> 4;
  const int a1[7] = {0,1,2,3,4,8,9};
  const int a2[7] = {-1,5,6,7,-1,-1,-1};
  const float4* wb = (const float4*)(Wp + (size_t)o*896 + kc*56);
  float acc = 0.f;
  #pragma unroll
  for (int i = 0; i < 14; ++i) {
    int cc2 = kc*56 + i*4;
    int s = cc2 >> 7, d0 = cc2 & 127;
    float4 a = *(const float4*)(vh + (a1[s]*16 + b)*D_ + d0);
    int s2 = a2[s];
    if (s2 >= 0) {
      float4 a2v = *(const float4*)(vh + (s2*16 + b)*D_ + d0);
      a.x += a2v.x; a.y += a2v.y; a.z += a2v.z; a.w += a2v.w;
    }
    a.x = fmaxf(a.x, 0.f); a.y = fmaxf(a.y, 0.f);
    a.z = fmaxf(a.z, 0.f); a.w = fmaxf(a.w, 0.f);
    float4 ww = wb[i];
    acc += a.x*ww.x + a.y*ww.y + a.z*ww.z + a.w*ww.w;
  }
  __shared__ float red[16][17];
  red[kc][b] = acc;
  __syncthreads();
  if (tid < 16) {
    float s = 0.f;
    #pragma unroll
    for (int k = 0; k < 16; ++k) s += red[k][tid];
    out[tid*OUT_ + o] = s + bp[o];
  }
}

// =====================================================================
extern "C" void kernel_launch(void* const* d_in, const int* in_sizes, int n_in,
                              void* d_out, int out_size, void* d_ws, size_t ws_size,
                              hipStream_t stream)
{
  (void)in_sizes; (void)n_in; (void)out_size; (void)ws_size;
  const int*   cc   = (const int*)  d_in[0];
  const int*   cp   = (const int*)  d_in[1];
  const int*   cd   = (const int*)  d_in[2];
  const int*   cli  = (const int*)  d_in[3];
  const int*   clv  = (const int*)  d_in[4];
  const int*   cii  = (const int*)  d_in[5];
  const int*   civ  = (const int*)  d_in[6];
  const float* wgt  = (const float*)d_in[7];
  const float* age  = (const float*)d_in[8];
  const float* ec   = (const float*)d_in[9];
  const float* ep   = (const float*)d_in[10];
  const float* ed   = (const float*)d_in[11];
  const float* eli  = (const float*)d_in[12];
  const float* elv  = (const float*)d_in[13];
  const float* eii  = (const float*)d_in[14];
  const float* eiv  = (const float*)d_in[15];
  const float* mWih = (const float*)d_in[16];
  const float* mWhh = (const float*)d_in[17];
  const float* mbih = (const float*)d_in[18];
  const float* mbhh = (const float*)d_in[19];
  const float* vWih = (const float*)d_in[20];
  const float* vWhh = (const float*)d_in[21];
  const float* vbih = (const float*)d_in[22];
  const float* vbhh = (const float*)d_in[23];
  const float* Wself= (const float*)d_in[24];
  const float* Wmsg = (const float*)d_in[25];
  const float* fwW  = (const float*)d_in[26];
  const float* fwB  = (const float*)d_in[27];
  const float* faW  = (const float*)d_in[28];
  const float* faB  = (const float*)d_in[29];
  const float* Wp   = (const float*)d_in[30];
  const float* bp   = (const float*)d_in[31];
  float* out = (float*)d_out;
  float* ws  = (float*)d_ws;

  float* vis   = ws + OFF_VIS;
  short* visb  = (short*)(ws + OFF_VISB);
  short* monb  = (short*)(ws + OFF_MONB);
  short* totb  = (short*)(ws + OFF_TOTB);
  short* w12t  = (short*)(ws + OFF_W12T);
  short* wihb  = (short*)(ws + OFF_WIHB);
  float* wihTv = ws + OFF_WIHTV;
  float* xe    = ws + OFF_XE;
  float* last  = ws + OFF_LAST;
  float* vh    = ws + OFF_VH;

  k_prepvis<<<3392, 256, 0, stream>>>(Wself, Wmsg, mWih, vWih, wgt, age,
                                      fwW, fwB, faW, faB,
                                      cc, cp, cd, ec, ep, ed,
                                      w12t, wihb, wihTv, xe, vis, visb);
  k_mon <<<16384, 128, 0, stream>>>(cli, clv, cii, civ, eli, elv, eii, eiv,
                                    vis, monb, totb);
  k_ggru<<<128, 512, 0, stream>>>(monb, totb, visb, w12t, wihb,
                                  mWhh, mbih, mbhh, last);
  k_vgru<<<160, 768, 0, stream>>>(last, xe, wihTv, vbih, vWhh, vbhh, vh);
  k_head<<<600, 256, 0, stream>>>(vh, Wp, bp, out);
}

// Round 7
// 248.213 us; speedup vs baseline: 1.6912x; 1.0151x over previous
//
#include <hip/hip_runtime.h>
#include <math.h>

#define B_   16
#define V_   16
#define C_   64
#define M_   32
#define CM_  16
#define D_   128
#define OUT_ 600
#define NSEQ 256      // B*V
#define NROW 8192     // B*V*M

typedef __attribute__((ext_vector_type(8))) short bf16x8;
typedef __attribute__((ext_vector_type(4))) short bf16x4;
typedef __attribute__((ext_vector_type(4))) float f32x4;

__device__ __forceinline__ unsigned short f2bf(float x) {
  union { float f; unsigned u; } v; v.f = x;
  unsigned r = v.u + 0x7fff + ((v.u >> 16) & 1);   // RNE
  return (unsigned short)(r >> 16);
}
__device__ __forceinline__ float bf2f(short s) {
  union { unsigned u; float f; } v;
  v.u = ((unsigned)(unsigned short)s) << 16;
  return v.f;
}
// fast sigmoid / tanh: native v_exp + v_rcp (~5 inst), saturate correctly
__device__ __forceinline__ float fsig(float x)  { return __fdividef(1.f, 1.f + __expf(-x)); }
__device__ __forceinline__ float ftanh(float x) { return 1.f - 2.f*__fdividef(1.f, __expf(2.f*x) + 1.f); }

// LDS-only barrier: drains LDS ops for cross-wave visibility but does NOT
// drain vmcnt — in-flight global prefetch loads survive the barrier.
__device__ __forceinline__ void ldsbar() {
  asm volatile("s_waitcnt lgkmcnt(0)" ::: "memory");
  __builtin_amdgcn_s_barrier();
  asm volatile("" ::: "memory");
}

// ---- workspace layout (float units; bf16 arrays are short* views) ----
constexpr int OFF_VIS   = 0;                               // fp32 [3][256][128]
constexpr int OFF_VISB  = 98304;                           // bf16 [3][256][128]
constexpr int OFF_MONB  = 147456;                          // bf16 [2][8192][128]
constexpr int OFF_TOTB  = 1196032;                         // bf16 [2][8192][128]
constexpr int OFF_W12T  = 2244608;                         // bf16 [8][128n][256k]
constexpr int OFF_WIHB  = 2375680;                         // bf16 [5][384n][128k]
constexpr int OFF_WIHTV = 2498560;                         // fp32 [4][128][384]
constexpr int OFF_XE    = 2695168;                         // fp32 [2][256][128]
constexpr int OFF_LAST  = 27926528;                        // fp32 [8][256][128]
constexpr int OFF_VH    = 29171712;                        // fp32 [10][16][128]

// =====================================================================
// prep+vis merged — verified, unchanged.
// =====================================================================
__global__ __launch_bounds__(256) void k_prepvis(
    const float* __restrict__ Wself, const float* __restrict__ Wmsg,
    const float* __restrict__ mWih,  const float* __restrict__ vWih,
    const float* __restrict__ wgt,   const float* __restrict__ age,
    const float* __restrict__ fwW,   const float* __restrict__ fwB,
    const float* __restrict__ faW,   const float* __restrict__ faB,
    const int* __restrict__ cc, const int* __restrict__ cp, const int* __restrict__ cd,
    const float* __restrict__ ec, const float* __restrict__ ep, const float* __restrict__ ed,
    short* __restrict__ w12t, short* __restrict__ wihb,
    float* __restrict__ wihTv, float* __restrict__ xe,
    float* __restrict__ vis, short* __restrict__ visb)
{
  int bx = blockIdx.x, tid = threadIdx.x;
  if (bx < 1024) {                      // w12t[pt][n][k] = bf16 combined
    int lin = bx*256 + tid;             // < 262144
    int pt = lin >> 15, rem = lin & 32767;
    int n = rem >> 8, k = rem & 255;
    float v;
    if (k < 128) v = Wself[pt*16384 + k*128 + n] - Wmsg[pt*16384 + k*128 + n]*(1.f/3.f);
    else         v = Wmsg[pt*16384 + (k-128)*128 + n]*(1.f/3.f);
    w12t[lin] = (short)f2bf(v);
  } else if (bx < 1984) {               // wihb = bf16(mWih) elementwise
    int lin = (bx-1024)*256 + tid;      // < 245760
    wihb[lin] = (short)f2bf(mWih[lin]);
  } else if (bx < 2752) {               // vgru Wih transpose fp32
    int lin = (bx-1984)*256 + tid;      // < 196608
    int g = lin / 49152, rem2 = lin % 49152;
    int k = rem2 / 384, j = rem2 % 384;
    wihTv[lin] = vWih[g*49152 + j*128 + k];
  } else if (bx < 3008) {               // xe for weight / age
    int lin = (bx-2752)*256 + tid;      // < 65536
    int which = lin >> 15, rem2 = lin & 32767;
    int n = rem2 >> 7, d = rem2 & 127;
    float x  = which ? age[n] : wgt[n];
    float Wv = which ? faW[d] : fwW[d];
    float bb = which ? faB[d] : fwB[d];
    xe[lin] = (x != 0.0f) ? (x*Wv + bb) : 0.0f;
  } else {                              // visit-event sum pools
    int idx = (bx-3008)*256 + tid;      // < 98304
    int type = idx >> 15;
    int r = idx & 32767;
    int bv = r >> 7, d = r & 127;
    const int*   codes = (type==0) ? cc : (type==1) ? cp : cd;
    const float* emb   = (type==0) ? ec : (type==1) ? ep : ed;
    float acc = 0.f;
    for (int c = 0; c < C_; ++c) {
      int code = codes[bv*C_ + c];
      acc += emb[code*D_ + d];
    }
    vis [(type*NSEQ + bv)*D_ + d] = acc;
    visb[(type*NSEQ + bv)*D_ + d] = (short)f2bf(acc);
  }
}

// =====================================================================
// monitor-event pools — unchanged (verified).
// =====================================================================
__global__ __launch_bounds__(128) void k_mon(
    const int* __restrict__ cli, const int* __restrict__ clv,
    const int* __restrict__ cii, const int* __restrict__ civ,
    const float* __restrict__ eli, const float* __restrict__ elv,
    const float* __restrict__ eii, const float* __restrict__ eiv,
    const float* __restrict__ vis,
    short* __restrict__ monb, short* __restrict__ totb)
{
  int p   = blockIdx.x >> 13;
  int bvm = blockIdx.x & 8191;
  int d   = threadIdx.x;
  const int* ci = p ? cii : cli;  const int* cv = p ? civ : clv;
  const float* ei = p ? eii : eli; const float* ev = p ? eiv : elv;
  float acc = 0.f;
  #pragma unroll
  for (int c = 0; c < CM_; ++c) {
    int iv = ci[bvm*CM_ + c];
    int vv = cv[bvm*CM_ + c];
    acc += ei[iv*D_ + d] * ev[vv*D_ + d];
  }
  int bv = bvm >> 5;
  float vsum = vis[bv*D_ + d] + vis[(NSEQ + bv)*D_ + d] + vis[(2*NSEQ + bv)*D_ + d];
  monb[(p*NROW + bvm)*D_ + d] = (short)f2bf(acc);
  totb[(p*NROW + bvm)*D_ + d] = (short)f2bf(acc + vsum);
}

// =====================================================================
// FUSED GNN+GI+monitor-GRU (k_ggru v2) — THIS ROUND: software-pipelined
// to ONE barrier per step. Key: Y(m+1) depends only on X(m+1), not h(m),
// so stage1 for m+1 runs INSIDE step m overlapped with the h-dependent
// stage2/3 chain. Ys double-buffered; one ldsbar covers Ys[nxt], hb[nxt]
// and Xl[cur] handoffs. Barriers per step: 2 -> 1; stage1 MFMAs fill the
// pipe while the activation chain runs.
// =====================================================================
__global__ __launch_bounds__(512, 1) void k_ggru(
    const short* __restrict__ monb, const short* __restrict__ totb,
    const short* __restrict__ visb, const short* __restrict__ w12t,
    const short* __restrict__ wihb, const float* __restrict__ mWhh,
    const float* __restrict__ mbih, const float* __restrict__ mbhh,
    float* __restrict__ last)
{
  const int run  = blockIdx.x >> 4;     // 0..7
  const int pair = blockIdx.x & 15;     // batch b
  const int p = run >> 2, t = run & 3;
  const int g = (run % 4 == 0) ? (run / 4) : (run % 4 + 1);
  const int tid = threadIdx.x;
  const int w = tid >> 6;               // wave 0..7 = hidden slice
  const int lane = tid & 63;
  const int c = lane & 15, q = lane >> 4;
  const int j = w*16 + c;               // hidden index 0..127

  __shared__ short hb[2][4][16][40];            // 10240 B (v8-verified layout)
  __shared__ __align__(16) short Ys[2][16][136];// 8704 B (double-buffered)
  __shared__ __align__(16) short Xl[2][4096];   // 16384 B, XOR-swizzled rows

  for (int idx = tid; idx < 2*4*16*40; idx += 512)
    ((short*)hb)[idx] = 0;

  // ---- stage1 B-frags: w12t[run][n=w*16+c][k], K=256 -> 8 frags ----
  bf16x8 bW12[8];
  #pragma unroll
  for (int kt = 0; kt < 8; ++kt)
    bW12[kt] = *(const bf16x8*)(w12t + (size_t)run*32768 + (size_t)(w*16+c)*256 + kt*32 + q*8);

  // ---- stage2 B-frags: wihb rows gate*128+j ----
  bf16x8 bWih[3][4];
  #pragma unroll
  for (int gate = 0; gate < 3; ++gate)
    #pragma unroll
    for (int kt = 0; kt < 4; ++kt)
      bWih[gate][kt] = *(const bf16x8*)(wihb + ((size_t)g*384 + gate*128 + j)*128 + kt*32 + q*8);

  // ---- stage3 B-frags: mWhh rows gate*128+j (fp32 -> bf16) ----
  bf16x8 bWhh[3][4];
  #pragma unroll
  for (int gate = 0; gate < 3; ++gate) {
    const float* wp = mWhh + ((size_t)g*384 + gate*128 + j)*128 + q*8;
    #pragma unroll
    for (int kt = 0; kt < 4; ++kt) {
      float4 lo = *(const float4*)(wp + kt*32);
      float4 hi = *(const float4*)(wp + kt*32 + 4);
      bf16x8 tt;
      tt[0]=(short)f2bf(lo.x); tt[1]=(short)f2bf(lo.y); tt[2]=(short)f2bf(lo.z); tt[3]=(short)f2bf(lo.w);
      tt[4]=(short)f2bf(hi.x); tt[5]=(short)f2bf(hi.y); tt[6]=(short)f2bf(hi.z); tt[7]=(short)f2bf(hi.w);
      bWhh[gate][kt] = tt;
    }
  }
  const float bs0 = mbih[g*384 +       j] + mbhh[g*384 +       j];
  const float bs1 = mbih[g*384 + 128 + j] + mbhh[g*384 + 128 + j];
  const float bi2 = mbih[g*384 + 256 + j];
  const float bh2 = mbhh[g*384 + 256 + j];

  // ---- X staging mapping: thread (r = tid>>5, u = tid&31) ----
  const int xr_ = tid >> 5, xu = tid & 31;
  const int bv = pair*16 + xr_;
  const short* fsrc;
  int fstride;                                   // shorts per step
  if (xu < 16) {
    if (t == 0) { fsrc = monb + ((size_t)p*NROW + (size_t)bv*32)*128 + xu*8; fstride = 128; }
    else        { fsrc = visb + ((size_t)(t-1)*NSEQ + bv)*128 + xu*8;        fstride = 0;   }
  } else {
    fsrc = totb + ((size_t)p*NROW + (size_t)bv*32)*128 + (xu-16)*8;          fstride = 128;
  }
  const int xdofs = xr_*256 + (((xu*16) ^ ((xr_&7)<<4)) >> 1);   // shorts
  short* xdst0 = &Xl[0][xdofs];
  short* xdst1 = &Xl[1][xdofs];

  // prologue: X(0) -> Xl[0], X(1) -> Xl[1]
  {
    bf16x8 x0 = *(const bf16x8*)fsrc;
    bf16x8 x1 = *(const bf16x8*)(fsrc + fstride);
    *(bf16x8*)xdst0 = x0;
    *(bf16x8*)xdst1 = x1;
  }
  float hf[4] = {0.f,0.f,0.f,0.f};
  const int ktw = w >> 1;               // j>>5
  const int kkw = (w & 1)*16 + c;       // j&31
  ldsbar();   // hb zero + X(0), X(1) visible

  // prologue stage1: Y(0) from Xl[0] -> Ys[0]
  {
    const char* xbase = (const char*)&Xl[0][0];
    f32x4 accY = (f32x4){0.f,0.f,0.f,0.f};
    #pragma unroll
    for (int kt = 0; kt < 8; ++kt) {
      bf16x8 aX = *(const bf16x8*)(xbase + c*512 + ((kt*64 + q*16) ^ ((c&7)<<4)));
      accY = __builtin_amdgcn_mfma_f32_16x16x32_bf16(aX, bW12[kt], accY, 0, 0, 0);
    }
    #pragma unroll
    for (int reg = 0; reg < 4; ++reg)
      Ys[0][q*4 + reg][w*16 + c] = (short)f2bf(fmaxf(accY[reg], 0.f));
  }
  ldsbar();   // Ys[0] ready

  #pragma unroll 1
  for (int m = 0; m < 32; ++m) {
    const int cur = m & 1, nxt = cur ^ 1;

    // issue X(m+2) global load early (hidden under this step)
    bf16x8 xnext;
    if (m < 30) xnext = *(const bf16x8*)(fsrc + (size_t)(m+2)*fstride);

    // ---- phase A: stage1 for step m+1: Y(m+1) from Xl[nxt] ----
    // (independent of h(m) — overlaps the stage2/3 chain below)
    f32x4 accY = (f32x4){0.f,0.f,0.f,0.f};
    if (m < 31) {
      const char* xbase = (const char*)&Xl[nxt][0];
      #pragma unroll
      for (int kt = 0; kt < 8; ++kt) {
        bf16x8 aX = *(const bf16x8*)(xbase + c*512 + ((kt*64 + q*16) ^ ((c&7)<<4)));
        accY = __builtin_amdgcn_mfma_f32_16x16x32_bf16(aX, bW12[kt], accY, 0, 0, 0);
      }
    }

    // ---- phase B: stage2+3 gate pre-acts from Ys[cur], hb[cur] ----
    bf16x8 ah[4], a2[4];
    #pragma unroll
    for (int kt = 0; kt < 4; ++kt) {
      ah[kt] = *(const bf16x8*)&hb[cur][kt][c][q*8];
      a2[kt] = *(const bf16x8*)&Ys[cur][c][kt*32 + q*8];
    }
    f32x4 acc0 = (f32x4){0.f,0.f,0.f,0.f};
    f32x4 acc1 = (f32x4){0.f,0.f,0.f,0.f};
    f32x4 aG2  = (f32x4){0.f,0.f,0.f,0.f};
    f32x4 aH2  = (f32x4){0.f,0.f,0.f,0.f};
    #pragma unroll
    for (int kt = 0; kt < 4; ++kt) {
      acc0 = __builtin_amdgcn_mfma_f32_16x16x32_bf16(ah[kt], bWhh[0][kt], acc0, 0, 0, 0);
      acc1 = __builtin_amdgcn_mfma_f32_16x16x32_bf16(ah[kt], bWhh[1][kt], acc1, 0, 0, 0);
      aH2  = __builtin_amdgcn_mfma_f32_16x16x32_bf16(ah[kt], bWhh[2][kt], aH2,  0, 0, 0);
    }
    #pragma unroll
    for (int kt = 0; kt < 4; ++kt) {
      acc0 = __builtin_amdgcn_mfma_f32_16x16x32_bf16(a2[kt], bWih[0][kt], acc0, 0, 0, 0);
      acc1 = __builtin_amdgcn_mfma_f32_16x16x32_bf16(a2[kt], bWih[1][kt], acc1, 0, 0, 0);
      aG2  = __builtin_amdgcn_mfma_f32_16x16x32_bf16(a2[kt], bWih[2][kt], aG2,  0, 0, 0);
    }

    // write Y(m+1) into Ys[nxt] (read at step m+1, after the barrier)
    if (m < 31) {
      #pragma unroll
      for (int reg = 0; reg < 4; ++reg)
        Ys[nxt][q*4 + reg][w*16 + c] = (short)f2bf(fmaxf(accY[reg], 0.f));
    }
    // write X(m+2) into Xl[cur] (its old contents consumed at step m-1)
    if (m < 30) *(bf16x8*)(cur ? xdst1 : xdst0) = xnext;

    // ---- lane-local GRU activation: (seq = q*4+reg, this j) ----
    #pragma unroll
    for (int reg = 0; reg < 4; ++reg) {
      float rr = fsig(acc0[reg] + bs0);
      float zz = fsig(acc1[reg] + bs1);
      float nn = ftanh(aG2[reg] + bi2 + rr*(aH2[reg] + bh2));
      float hnew = (1.f - zz)*nn + zz*hf[reg];
      hf[reg] = hnew;
      hb[nxt][ktw][q*4 + reg][kkw] = (short)f2bf(hnew);
    }
    ldsbar();   // ONE barrier: Ys[nxt] + hb[nxt] + Xl[cur] visible for m+1
  }

  #pragma unroll
  for (int reg = 0; reg < 4; ++reg)
    last[((size_t)run*NSEQ + pair*16 + q*4 + reg)*D_ + j] = hf[reg];
}

// =====================================================================
// visit-level GRU v3 (vgi fused) — verified, unchanged.
// =====================================================================
__global__ __launch_bounds__(768) void k_vgru(
    const float* __restrict__ last, const float* __restrict__ xe,
    const float* __restrict__ wihTv, const float* __restrict__ vbih,
    const float* __restrict__ vWhh, const float* __restrict__ vbhh,
    float* __restrict__ vh)
{
  int run = blockIdx.x >> 4, b = blockIdx.x & 15;
  int tid = threadIdx.x;
  int vidx = (run < 4) ? 0 : (run < 8) ? 1 : (run - 6);

  __shared__ float Xs[16][128];          // 8 KB
  __shared__ float giL[16*384];          // 24 KB
  __shared__ __align__(16) float hsv[128];
  __shared__ float gh[384];

  const float* X = (run < 8) ? (last + ((size_t)run*NSEQ + b*16)*D_)
                             : (xe + ((size_t)(run-8)*NSEQ + b*16)*D_);
  for (int idx = tid; idx < 2048; idx += 768)
    ((float*)Xs)[idx] = X[idx];
  if (tid < 128) hsv[tid] = 0.f;
  __syncthreads();

  // ---- gi precompute into LDS: thread (half, j) does 8 visits ----
  {
    int half = (tid >= 384) ? 1 : 0;
    int j = tid - half*384;
    float accv[8];
    float bias = vbih[vidx*384 + j];
    #pragma unroll
    for (int s = 0; s < 8; ++s) accv[s] = bias;
    const float* W = wihTv + vidx*49152 + j;
    #pragma unroll 4
    for (int k = 0; k < 128; ++k) {
      float wv = W[k*384];
      #pragma unroll
      for (int s = 0; s < 8; ++s) accv[s] += Xs[half*8 + s][k] * wv;
    }
    #pragma unroll
    for (int s = 0; s < 8; ++s)
      giL[(half*8 + s)*384 + j] = accv[s];
  }

  // ---- recurrence weights (pair-split, w[64]/thread, no spill) ----
  int j = tid >> 1, kh = tid & 1;
  float w[64];
  const float4* wrow = (const float4*)(vWhh + (vidx*384 + j)*128 + kh*64);
  #pragma unroll
  for (int k4 = 0; k4 < 16; ++k4) {
    float4 t4 = wrow[k4];
    w[4*k4] = t4.x; w[4*k4+1] = t4.y; w[4*k4+2] = t4.z; w[4*k4+3] = t4.w;
  }
  float bj = vbhh[vidx*384 + j];
  __syncthreads();

  #pragma unroll 1
  for (int v = 0; v < 16; ++v) {
    const float4* h4 = (const float4*)(hsv + kh*64);
    float p0 = 0.f, p1 = 0.f;
    #pragma unroll
    for (int k4 = 0; k4 < 8; ++k4) {
      float4 u0 = h4[k4], u1 = h4[k4+8];
      p0 += w[4*k4   ]*u0.x + w[4*k4+1 ]*u0.y + w[4*k4+2 ]*u0.z + w[4*k4+3 ]*u0.w;
      p1 += w[4*k4+32]*u1.x + w[4*k4+33]*u1.y + w[4*k4+34]*u1.z + w[4*k4+35]*u1.w;
    }
    float part = p0 + p1;
    part += __shfl_xor(part, 1);
    if (kh == 0) gh[j] = bj + ((j < 256) ? giL[v*384 + j] : 0.f) + part;
    __syncthreads();
    if (tid < 128) {
      float r = fsig(gh[tid]);
      float z = fsig(gh[tid+128]);
      float gin = giL[v*384 + 256 + tid];
      float n = ftanh(gin + r*gh[tid+256]);
      hsv[tid] = (1.f - z)*n + z*hsv[tid];
    }
    __syncthreads();
  }
  if (tid < 128) vh[(run*16 + b)*D_ + tid] = hsv[tid];
}

// =====================================================================
// head v4 (pe fused) — verified, unchanged.
// =====================================================================
__global__ __launch_bounds__(256) void k_head(
    const float* __restrict__ vh, const float* __restrict__ Wp,
    const float* __restrict__ bp, float* __restrict__ out)
{
  const int o = blockIdx.x;
  const int tid = threadIdx.x;
  const int b = tid & 15, kc = tid >> 4;
  const int a1[7] = {0,1,2,3,4,8,9};
  const int a2[7] = {-1,5,6,7,-1,-1,-1};
  const float4* wb = (const float4*)(Wp + (size_t)o*896 + kc*56);
  float acc = 0.f;
  #pragma unroll
  for (int i = 0; i < 14; ++i) {
    int cc2 = kc*56 + i*4;
    int s = cc2 >> 7, d0 = cc2 & 127;
    float4 a = *(const float4*)(vh + (a1[s]*16 + b)*D_ + d0);
    int s2 = a2[s];
    if (s2 >= 0) {
      float4 a2v = *(const float4*)(vh + (s2*16 + b)*D_ + d0);
      a.x += a2v.x; a.y += a2v.y; a.z += a2v.z; a.w += a2v.w;
    }
    a.x = fmaxf(a.x, 0.f); a.y = fmaxf(a.y, 0.f);
    a.z = fmaxf(a.z, 0.f); a.w = fmaxf(a.w, 0.f);
    float4 ww = wb[i];
    acc += a.x*ww.x + a.y*ww.y + a.z*ww.z + a.w*ww.w;
  }
  __shared__ float red[16][17];
  red[kc][b] = acc;
  __syncthreads();
  if (tid < 16) {
    float s = 0.f;
    #pragma unroll
    for (int k = 0; k < 16; ++k) s += red[k][tid];
    out[tid*OUT_ + o] = s + bp[o];
  }
}

// =====================================================================
extern "C" void kernel_launch(void* const* d_in, const int* in_sizes, int n_in,
                              void* d_out, int out_size, void* d_ws, size_t ws_size,
                              hipStream_t stream)
{
  (void)in_sizes; (void)n_in; (void)out_size; (void)ws_size;
  const int*   cc   = (const int*)  d_in[0];
  const int*   cp   = (const int*)  d_in[1];
  const int*   cd   = (const int*)  d_in[2];
  const int*   cli  = (const int*)  d_in[3];
  const int*   clv  = (const int*)  d_in[4];
  const int*   cii  = (const int*)  d_in[5];
  const int*   civ  = (const int*)  d_in[6];
  const float* wgt  = (const float*)d_in[7];
  const float* age  = (const float*)d_in[8];
  const float* ec   = (const float*)d_in[9];
  const float* ep   = (const float*)d_in[10];
  const float* ed   = (const float*)d_in[11];
  const float* eli  = (const float*)d_in[12];
  const float* elv  = (const float*)d_in[13];
  const float* eii  = (const float*)d_in[14];
  const float* eiv  = (const float*)d_in[15];
  const float* mWih = (const float*)d_in[16];
  const float* mWhh = (const float*)d_in[17];
  const float* mbih = (const float*)d_in[18];
  const float* mbhh = (const float*)d_in[19];
  const float* vWih = (const float*)d_in[20];
  const float* vWhh = (const float*)d_in[21];
  const float* vbih = (const float*)d_in[22];
  const float* vbhh = (const float*)d_in[23];
  const float* Wself= (const float*)d_in[24];
  const float* Wmsg = (const float*)d_in[25];
  const float* fwW  = (const float*)d_in[26];
  const float* fwB  = (const float*)d_in[27];
  const float* faW  = (const float*)d_in[28];
  const float* faB  = (const float*)d_in[29];
  const float* Wp   = (const float*)d_in[30];
  const float* bp   = (const float*)d_in[31];
  float* out = (float*)d_out;
  float* ws  = (float*)d_ws;

  float* vis   = ws + OFF_VIS;
  short* visb  = (short*)(ws + OFF_VISB);
  short* monb  = (short*)(ws + OFF_MONB);
  short* totb  = (short*)(ws + OFF_TOTB);
  short* w12t  = (short*)(ws + OFF_W12T);
  short* wihb  = (short*)(ws + OFF_WIHB);
  float* wihTv = ws + OFF_WIHTV;
  float* xe    = ws + OFF_XE;
  float* last  = ws + OFF_LAST;
  float* vh    = ws + OFF_VH;

  k_prepvis<<<3392, 256, 0, stream>>>(Wself, Wmsg, mWih, vWih, wgt, age,
                                      fwW, fwB, faW, faB,
                                      cc, cp, cd, ec, ep, ed,
                                      w12t, wihb, wihTv, xe, vis, visb);
  k_mon <<<16384, 128, 0, stream>>>(cli, clv, cii, civ, eli, elv, eii, eiv,
                                    vis, monb, totb);
  k_ggru<<<128, 512, 0, stream>>>(monb, totb, visb, w12t, wihb,
                                  mWhh, mbih, mbhh, last);
  k_vgru<<<160, 768, 0, stream>>>(last, xe, wihTv, vbih, vWhh, vbhh, vh);
  k_head<<<600, 256, 0, stream>>>(vh, Wp, bp, out);
}